// Round 7
// baseline (34635.300 us; speedup 1.0000x reference)
//
#include <hip/hip_runtime.h>
#include <stdint.h>
#include <stddef.h>

#define T_STEPS 512
#define B_SZ    128
#define DIN     1024
#define H_SZ    2048
#define NG      8192            // 4*H
#define BH      (B_SZ * H_SZ)   // 262144
#define NREP    8               // h replicas, one per XCD
#define HSLOT   ((size_t)NREP * BH)

typedef __attribute__((ext_vector_type(8))) short bf16x8;
typedef __attribute__((ext_vector_type(4))) float f32x4;

static __device__ __forceinline__ unsigned short f2bf(float x) {
  unsigned int u = __float_as_uint(x);
  u += 0x7fffu + ((u >> 16) & 1u);   // RNE; inputs finite
  return (unsigned short)(u >> 16);
}

static __device__ __forceinline__ float sigm(float x) {
  return 1.0f / (1.0f + __expf(-x));
}
static __device__ __forceinline__ float tanh_(float x) {
  float e = __expf(-2.0f * fabsf(x));  // in (0,1], no overflow
  float t = (1.0f - e) / (1.0f + e);
  return x < 0.0f ? -t : t;
}

// global -> LDS async copy, 16B per lane. LDS dest is wave-uniform base;
// HW writes lane l at ldst + l*16. Global src IS per-lane (swizzle there).
static __device__ __forceinline__ void async_load16(const void* gsrc, void* ldst) {
  __builtin_amdgcn_global_load_lds(
      (__attribute__((address_space(1))) void*)(const_cast<void*>(gsrc)),
      (__attribute__((address_space(3))) void*)ldst,
      16, 0, 0);
}

// Barrier that memory ops cannot be compiler-moved across (rd4's NaN fix).
static __device__ __forceinline__ void wg_barrier_pinned() {
  __builtin_amdgcn_s_barrier();
  asm volatile("" ::: "memory");
  __builtin_amdgcn_sched_barrier(0);
}

__global__ void cvt_x_bf16(const float4* __restrict__ in, ushort4* __restrict__ out, int n4) {
  int i = blockIdx.x * blockDim.x + threadIdx.x;
  int st = gridDim.x * blockDim.x;
  for (; i < n4; i += st) {
    float4 v = in[i];
    ushort4 o;
    o.x = f2bf(v.x); o.y = f2bf(v.y); o.z = f2bf(v.z); o.w = f2bf(v.w);
    out[i] = o;
  }
}

__global__ void build_wcat(const float* __restrict__ wa, const float* __restrict__ wb,
                           unsigned short* __restrict__ outw, int ka, int K) {
  int k = blockIdx.x * blockDim.x + threadIdx.x;
  int n = blockIdx.y;
  if (k >= K) return;
  int kb = K - ka;
  float v = (k < ka) ? wa[(size_t)n * ka + k]
                     : wb[(size_t)n * kb + (k - ka)];
  outw[(size_t)n * K + k] = f2bf(v);
}

__global__ void init_state(const float* __restrict__ h0, const float* __restrict__ c0,
                           unsigned short* __restrict__ hb0, unsigned short* __restrict__ hb1,
                           float* __restrict__ cws) {
  int i = blockIdx.x * blockDim.x + threadIdx.x;
  if (i < BH) {
    unsigned short v0 = f2bf(h0[i]);
    unsigned short v1 = f2bf(h0[BH + i]);
#pragma unroll
    for (int rp = 0; rp < NREP; ++rp) {
      hb0[(size_t)rp * BH + i] = v0;   // slot 0 replicas
      hb1[(size_t)rp * BH + i] = v1;
    }
    cws[i] = c0[i];
    cws[BH + i] = c0[BH + i];
  }
}

// One LSTM cell step. gates[128,8192] = A[128,K] @ Wcat^T + b; A = concat(a0|a1).
// WG owns 8 h-cols (32 gate-cols). Wave wv owns rows [wv*32, wv*32+32).
// A-fragments: direct global->register (XCD-local replica), 4 named sets, 4-ahead.
// B (weights): LDS ring of 8 x 4KB, staged 7 ahead via global_load_lds, XOR-swizzled.
// h-output written to all NREP replicas (stride BH) so next step reads XCD-local.
template<int K, int KSPLIT>
static __device__ __forceinline__ void lstm_step_body(
    unsigned short (*Bbuf)[32 * 64],
    const unsigned short* __restrict__ a0,   // [128][KSPLIT] row-major (replica-adjusted)
    const unsigned short* __restrict__ a1,   // [128][H_SZ] row-major (replica-adjusted)
    const unsigned short* __restrict__ w,    // [NG][K] bf16
    const float* __restrict__ bias,          // [NG] fp32
    float* __restrict__ c,                   // [B][H] fp32, in-place (WG-private cols)
    unsigned short* __restrict__ hout,       // [B][H] bf16, replica 0 base
    float* __restrict__ fout,                // optional [B][H] fp32
    int tid, int lane, int wv, int n0)
{
  constexpr int KT = K >> 6;   // 48 or 64, divisible by 4
  f32x4 acc[2][2] = {};

  const unsigned short* r0p[2];
  const unsigned short* r1p[2];
#pragma unroll
  for (int rt = 0; rt < 2; ++rt) {
    int row = wv * 32 + rt * 16 + (lane & 15);
    r0p[rt] = a0 + (size_t)row * KSPLIT;
    r1p[rt] = a1 + (size_t)row * H_SZ;
  }
  const int klo = (lane >> 4) << 3;   // lane-group k offset (elems)

  auto loadA = [&](int kt, bf16x8 (&A)[2][2]) {
    const int kb = kt << 6;
    const bool sA = kb < KSPLIT;     // tiles never straddle (KSPLIT % 64 == 0)
    const int off = (sA ? kb : kb - KSPLIT) + klo;
#pragma unroll
    for (int rt = 0; rt < 2; ++rt) {
      const unsigned short* bp = (sA ? r0p[rt] : r1p[rt]) + off;
      A[rt][0] = *(const bf16x8*)(bp);
      A[rt][1] = *(const bf16x8*)(bp + 32);
    }
  };

  auto stageB = [&](int kt) {
    const int kb = kt << 6;
    int nl  = tid >> 3;                              // 32 gate-rows
    int chs = (tid & 7) ^ (nl & 7);                  // pre-swizzled source chunk
    int nn  = ((nl >> 3) << 11) + n0 + (nl & 7);     // gate*2048 + hcol
    const unsigned short* src = w + (size_t)nn * K + kb + (chs << 3);
    async_load16(src, &Bbuf[kt & 7][(wv * 64) * 8]);
  };

  auto iter = [&](int kt, bf16x8 (&A)[2][2]) {
    if (kt + 7 < KT) stageB(kt + 7);                 // issue stage early
    const int bq = kt & 7;
#pragma unroll
    for (int kkk = 0; kkk < 2; ++kkk) {
      bf16x8 bfr[2];
#pragma unroll
      for (int ct = 0; ct < 2; ++ct) {
        int nl = ct * 16 + (lane & 15);
        int ch = kkk * 4 + (lane >> 4);
        bfr[ct] = *(const bf16x8*)&Bbuf[bq][nl * 64 + ((ch ^ (nl & 7)) << 3)];
      }
#pragma unroll
      for (int rt = 0; rt < 2; ++rt)
#pragma unroll
        for (int ct = 0; ct < 2; ++ct)
          acc[rt][ct] = __builtin_amdgcn_mfma_f32_16x16x32_bf16(A[rt][kkk], bfr[ct], acc[rt][ct], 0, 0, 0);
    }
    if (kt + 4 < KT) loadA(kt + 4, A);               // refill own named set post-use
    // Ladder: retire own B(kt+1) before the barrier (exact in-order count;
    // also subsumed by the compiler's A-register waits via FIFO retirement).
    int rem = KT - 1 - kt;
    if (rem >= 7)      asm volatile("s_waitcnt vmcnt(34)" ::: "memory");
    else if (rem == 6) asm volatile("s_waitcnt vmcnt(33)" ::: "memory");
    else if (rem == 5) asm volatile("s_waitcnt vmcnt(32)" ::: "memory");
    else if (rem == 4) asm volatile("s_waitcnt vmcnt(31)" ::: "memory");
    else if (rem == 3) asm volatile("s_waitcnt vmcnt(26)" ::: "memory");
    else if (rem == 2) asm volatile("s_waitcnt vmcnt(21)" ::: "memory");
    else if (rem == 1) asm volatile("s_waitcnt vmcnt(16)" ::: "memory");
    wg_barrier_pinned();   // rem==0: plain pinned barrier (reads already consumed)
  };

  bf16x8 A0[2][2], A1[2][2], A2[2][2], A3[2][2];
  // Prologue queue: B0,A0x4,B1,A1x4,B2,A2x4,B3,A3x4,B4,B5,B6 = 23 ops; retire B0.
  stageB(0); loadA(0, A0);
  stageB(1); loadA(1, A1);
  stageB(2); loadA(2, A2);
  stageB(3); loadA(3, A3);
  stageB(4); stageB(5); stageB(6);
  asm volatile("s_waitcnt vmcnt(22)" ::: "memory");
  wg_barrier_pinned();

  for (int kt = 0; kt < KT; kt += 4) {
    iter(kt,     A0);
    iter(kt + 1, A1);
    iter(kt + 2, A2);
    iter(kt + 3, A3);
  }

  // Epilogue. C/D map: col(nl)=lane&15, row=(lane>>4)*4+r.
  // acc[rt][0] = gate i (col<8) or f; acc[rt][1] = g or o.
  const int hc  = n0 + (lane & 7);
  const float bi  = bias[hc];
  const float bff = bias[H_SZ + hc];
  const float bg  = bias[2 * H_SZ + hc];
  const float bo  = bias[3 * H_SZ + hc];
  const int hi8 = (lane >> 3) & 1;

#pragma unroll
  for (int r = 0; r < 4; ++r) {
    float vA0 = acc[0][0][r], vA1 = acc[0][1][r];
    float vB0 = acc[1][0][r], vB1 = acc[1][1][r];
    float sA0 = __shfl_xor(vA0, 8), sA1 = __shfl_xor(vA1, 8);
    float sB0 = __shfl_xor(vB0, 8), sB1 = __shfl_xor(vB1, 8);
    float gi, gf, gg, go; int rtm;
    if (!hi8) { gi = vA0; gf = sA0; gg = vA1; go = sA1; rtm = 0; }
    else      { gi = sB0; gf = vB0; gg = sB1; go = vB1; rtm = 1; }
    int row = wv * 32 + rtm * 16 + ((lane >> 4) << 2) + r;
    size_t idx = (size_t)row * H_SZ + hc;
    float iv = sigm(gi + bi);
    float fv = sigm(gf + bff);
    float gv = tanh_(gg + bg);
    float ov = sigm(go + bo);
    float cn = fv * c[idx] + iv * gv;
    c[idx] = cn;
    float hn = ov * tanh_(cn);
    unsigned short hbf = f2bf(hn);
#pragma unroll
    for (int rp = 0; rp < NREP; ++rp)
      hout[idx + (size_t)rp * BH] = hbf;   // write all XCD replicas
    if (fout) fout[idx] = hn;
  }
}

// Single step (edges of the schedule). a0rep/a1rep: BH if that operand is an
// h-replica array (read XCD-local copy), else 0.
template<int K, int KSPLIT>
__global__ __launch_bounds__(256) void lstm_one(
    const unsigned short* __restrict__ a0, size_t a0rep,
    const unsigned short* __restrict__ a1, size_t a1rep,
    const unsigned short* __restrict__ w,  const float* __restrict__ bias,
    float* __restrict__ c, unsigned short* __restrict__ hout, float* __restrict__ fout)
{
  __shared__ __align__(16) unsigned short Bbuf[8][32 * 64];   // 32 KB
  const int tid = threadIdx.x, lane = tid & 63, wv = tid >> 6, n0 = blockIdx.x << 3;
  const size_t xcd = blockIdx.x & (NREP - 1);
  lstm_step_body<K, KSPLIT>(Bbuf, a0 + xcd * a0rep, a1 + xcd * a1rep,
                            w, bias, c, hout, fout, tid, lane, wv, n0);
}

// Fused pair: L1(t) then L0(t+1). Bodies are independent (read only buffers
// published at the preceding dispatch boundary; writes read only after the
// next boundary) -> no internal grid sync; pipelines overlap at the seam.
template<int K1, int KS1, int K2, int KS2>
__global__ __launch_bounds__(256) void lstm_pair(
    const unsigned short* __restrict__ a0_1, size_t a0rep1,
    const unsigned short* __restrict__ a1_1, size_t a1rep1,
    const unsigned short* __restrict__ w1,   const float* __restrict__ bias1,
    float* __restrict__ c1, unsigned short* __restrict__ h1out,
    const unsigned short* __restrict__ a0_2, size_t a0rep2,
    const unsigned short* __restrict__ a1_2, size_t a1rep2,
    const unsigned short* __restrict__ w2,   const float* __restrict__ bias2,
    float* __restrict__ c2, unsigned short* __restrict__ h2out)
{
  __shared__ __align__(16) unsigned short Bbuf[8][32 * 64];   // 32 KB
  const int tid = threadIdx.x, lane = tid & 63, wv = tid >> 6, n0 = blockIdx.x << 3;
  const size_t xcd = blockIdx.x & (NREP - 1);
  lstm_step_body<K1, KS1>(Bbuf, a0_1 + xcd * a0rep1, a1_1 + xcd * a1rep1,
                          w1, bias1, c1, h1out, nullptr, tid, lane, wv, n0);
  lstm_step_body<K2, KS2>(Bbuf, a0_2 + xcd * a0rep2, a1_2 + xcd * a1rep2,
                          w2, bias2, c2, h2out, nullptr, tid, lane, wv, n0);
}

extern "C" void kernel_launch(void* const* d_in, const int* in_sizes, int n_in,
                              void* d_out, int out_size, void* d_ws, size_t ws_size,
                              hipStream_t stream) {
  (void)in_sizes; (void)n_in; (void)out_size; (void)ws_size;
  const float* x    = (const float*)d_in[0];
  const float* h0   = (const float*)d_in[1];
  const float* c0   = (const float*)d_in[2];
  const float* Wih0 = (const float*)d_in[3];
  const float* Whh0 = (const float*)d_in[4];
  const float* b0   = (const float*)d_in[5];
  const float* Wih1 = (const float*)d_in[6];
  const float* Whh1 = (const float*)d_in[7];
  const float* b1   = (const float*)d_in[8];
  float* out = (float*)d_out;

  // workspace: xbf 134MB | Wc0 50MB | Wc1 67MB | hb0 2 slots x 8 reps x BH (8.4MB)
  //            | hb1 same | cws 2MB  -> ~270 MB total
  unsigned short* xbf = (unsigned short*)d_ws;
  unsigned short* Wc0 = xbf + (size_t)T_STEPS * B_SZ * DIN;
  unsigned short* Wc1 = Wc0 + (size_t)NG * 3072;
  unsigned short* hb0 = Wc1 + (size_t)NG * 4096;          // 2 * HSLOT
  unsigned short* hb1 = hb0 + 2 * HSLOT;                  // 2 * HSLOT
  float*          cws = (float*)(hb1 + 2 * HSLOT);        // 2 * BH fp32

  cvt_x_bf16<<<dim3(4096), dim3(256), 0, stream>>>(
      (const float4*)x, (ushort4*)xbf, T_STEPS * B_SZ * DIN / 4);
  build_wcat<<<dim3(12, NG), dim3(256), 0, stream>>>(Wih0, Whh0, Wc0, DIN, 3072);
  build_wcat<<<dim3(16, NG), dim3(256), 0, stream>>>(Wih1, Whh1, Wc1, H_SZ, 4096);
  init_state<<<dim3(BH / 256), dim3(256), 0, stream>>>(h0, c0, hb0, hb1, cws);

  // Schedule: L0(0); { L1(t) + L0(t+1) } t=0..510; L1(511)->out.
  // h slots: L0(t) reads hb0 slot[t&1], writes slot[(t+1)&1] (all replicas);
  //          L1(t) reads hb0 slot[(t+1)&1] + hb1 slot[t&1], writes hb1 slot[(t+1)&1].
  lstm_one<3072, 1024><<<dim3(256), dim3(256), 0, stream>>>(
      xbf, 0, hb0 + 0, BH, Wc0, b0, cws, hb0 + HSLOT, nullptr);

  for (int t = 0; t < T_STEPS - 1; ++t) {
    unsigned short* h0cur = hb0 + (size_t)((t + 1) & 1) * HSLOT;
    lstm_pair<4096, 2048, 3072, 1024><<<dim3(256), dim3(256), 0, stream>>>(
        /*L1(t)*/   h0cur, BH, hb1 + (size_t)(t & 1) * HSLOT, BH, Wc1, b1,
                    cws + BH, hb1 + (size_t)((t + 1) & 1) * HSLOT,
        /*L0(t+1)*/ xbf + (size_t)(t + 1) * B_SZ * DIN, 0, h0cur, BH, Wc0, b0,
                    cws, hb0 + (size_t)(t & 1) * HSLOT);
  }
  // L1(511): reads hb0 slot0, hb1 slot1; writes hb1 slot0 + fp32 out.
  lstm_one<4096, 2048><<<dim3(256), dim3(256), 0, stream>>>(
      hb0 + 0, BH, hb1 + HSLOT, BH, Wc1, b1, cws + BH, hb1 + 0, out);
}